// Round 6
// baseline (1786.164 us; speedup 1.0000x reference)
//
#include <hip/hip_runtime.h>

#define HH 64
#define WW 64
#define CC 128
#define HWSZ 4096   // 64*64

// ---------------------------------------------------------------------------
// Direct 3x3 conv v4, pad 1, stride 1.
// Block: 256 threads, 32x32 px tile, 4 output channels.
// Thread: 4 consecutive px (x-quad) x 4 oc = 16 acc.
// ALL weights for this block's 4 oc staged in LDS ONCE up front (18.4 KB),
// read in the inner loop as one b128 broadcast per (ic,k) -- conflict-free.
// x staged in LDS in 8-ic chunks (39.2 KB).  Inner loop per ic:
// 6 ds_read_b128 (window) + 9 ds_read_b128 (weights) + 144 FMA.
// BN_IN fuses relu(bn()) into input staging; STATS accumulates per-channel
// sum/sumsq; ATOMIC = ic-split accumulation (offset conv).
// ---------------------------------------------------------------------------
template<int TAG, bool BN_IN, bool STATS, bool ATOMIC>
__global__ __launch_bounds__(256)
void conv_k(const float* __restrict__ in, const float* __restrict__ wgt,
            const float* __restrict__ bias,
            const float* __restrict__ bnscale, const float* __restrict__ bnshift,
            float* __restrict__ out, float* __restrict__ ssum, float* __restrict__ ssq,
            int oc_total, int ocg_count, int n_split)
{
    __shared__ float xt[8][34 * 36];     // 39.2 KB
    __shared__ float wt[CC][9][4];       // 18.4 KB (only icps rows used)
    const int tid = threadIdx.x;
    const int q  = tid & 7;              // x-quad index, px0 = 4q
    const int ty = tid >> 3;             // 0..31
    const int bx = blockIdx.x * 32, by = blockIdx.y * 32;
    int z = blockIdx.z;
    const int split = z % n_split; z /= n_split;
    const int ocg = z % ocg_count;
    const int b = z / ocg_count;
    const int oc0 = ocg * 4;
    const int icps = CC / n_split;
    const int ic_start = split * icps;

    // stage this block's weights once: wt[ic_rel][k][o]
    for (int i = tid; i < icps * 36; i += 256) {
        int icr = i / 36;
        int rem = i - icr * 36;
        int k = rem >> 2, o = rem & 3;
        int oc = oc0 + o;
        wt[icr][k][o] = (oc < oc_total)
            ? wgt[((size_t)oc * CC + (ic_start + icr)) * 9 + k] : 0.f;
    }

    float acc[4][4];   // [px][oc]
#pragma unroll
    for (int o = 0; o < 4; ++o) {
        float bv = 0.f;
        if (!ATOMIC || split == 0)
            bv = (oc0 + o < oc_total) ? bias[min(oc0 + o, oc_total - 1)] : 0.f;
#pragma unroll
        for (int p = 0; p < 4; ++p) acc[p][o] = bv;
    }

    const float* inb = in + (size_t)b * CC * HWSZ;

    for (int ic0 = ic_start; ic0 < ic_start + icps; ic0 += 8) {
        __syncthreads();   // protects xt reuse; first iter also fences wt staging
        for (int i = tid; i < 8 * 34 * 36; i += 256) {
            int ic = i / 1224;
            int rem = i - ic * 1224;
            int r = rem / 36, cl = rem - r * 36;
            int gy = by + r - 1, gx = bx + cl - 1;
            float v = 0.f;
            if (cl < 35 && (unsigned)gy < (unsigned)HH && (unsigned)gx < (unsigned)WW) {
                v = inb[(ic0 + ic) * HWSZ + gy * WW + gx];
                if (BN_IN)
                    v = fmaxf(fmaf(v, bnscale[ic0 + ic], bnshift[ic0 + ic]), 0.f);
            }
            xt[ic][rem] = v;
        }
        __syncthreads();
#pragma unroll
        for (int ic = 0; ic < 8; ++ic) {
            const int icr = ic0 - ic_start + ic;
            // window: 2 x b128 per row, 3 rows
            float win[3][8];
#pragma unroll
            for (int ky = 0; ky < 3; ++ky) {
                const float4* rp = reinterpret_cast<const float4*>(&xt[ic][(ty + ky) * 36 + 4 * q]);
                float4 lo = rp[0], hi = rp[1];
                win[ky][0] = lo.x; win[ky][1] = lo.y; win[ky][2] = lo.z; win[ky][3] = lo.w;
                win[ky][4] = hi.x; win[ky][5] = hi.y; win[ky][6] = hi.z; win[ky][7] = hi.w;
            }
#pragma unroll
            for (int k = 0; k < 9; ++k) {
                const int ky = k / 3, kx = k % 3;
                float4 w4 = *reinterpret_cast<const float4*>(&wt[icr][k][0]);  // broadcast
                float wv[4] = {w4.x, w4.y, w4.z, w4.w};
#pragma unroll
                for (int o = 0; o < 4; ++o)
#pragma unroll
                    for (int p = 0; p < 4; ++p)
                        acc[p][o] = fmaf(win[ky][p + kx], wv[o], acc[p][o]);
            }
        }
    }

    const int py = by + ty;
    const int px0 = bx + 4 * q;
#pragma unroll
    for (int o = 0; o < 4; ++o) {
        int oc = oc0 + o;
        if (ATOMIC) {
            if (oc < oc_total) {
                float* op = out + ((size_t)b * oc_total + oc) * HWSZ + py * WW + px0;
#pragma unroll
                for (int p = 0; p < 4; ++p) atomicAdd(op + p, acc[p][o]);
            }
        } else {
            float4 v = make_float4(acc[0][o], acc[1][o], acc[2][o], acc[3][o]);
            *reinterpret_cast<float4*>(out + ((size_t)b * oc_total + oc) * HWSZ + py * WW + px0) = v;
        }
    }

    if (STATS) {
#pragma unroll
        for (int o = 0; o < 4; ++o) {
            float s = acc[0][o] + acc[1][o] + acc[2][o] + acc[3][o];
            float qq = acc[0][o] * acc[0][o] + acc[1][o] * acc[1][o]
                     + acc[2][o] * acc[2][o] + acc[3][o] * acc[3][o];
            for (int d = 32; d > 0; d >>= 1) {
                s  += __shfl_down(s, d);
                qq += __shfl_down(qq, d);
            }
            if ((tid & 63) == 0) {
                atomicAdd(&ssum[oc0 + o], s);
                atomicAdd(&ssq[oc0 + o], qq);
            }
        }
    }
}

// ---------------------------------------------------------------------------
// Deformable 3x3 conv v4 (deform_groups=1, pad 1, stride 1, zero-pad).
// 1 px x 16 oc per thread.  ALL weights for the block's 16 oc staged in LDS
// once (73.7 KB), read as 4 b128 broadcasts per (ic,k).  Bilinear gathers
// stay GLOBAL (zero bank conflicts; validity-folded weights + clamped
// indices are correct for arbitrary offsets).  unroll 2 lets the compiler
// prefetch the next ic's gathers under the current ic's FMAs.
// ---------------------------------------------------------------------------
__global__ __launch_bounds__(256)
void dconv_k(const float* __restrict__ x, const float* __restrict__ off,
             const float* __restrict__ wd, const float* __restrict__ bd,
             float* __restrict__ dout)
{
    __shared__ float wt[CC][9][16];    // 73.7 KB
    const int tid = threadIdx.x;
    const int tx = tid & 15, ty = tid >> 4;
    const int px = blockIdx.x * 16 + tx;
    const int py = blockIdx.y * 16 + ty;
    const int b = blockIdx.z >> 3;
    const int oc0 = (blockIdx.z & 7) * 16;

    // stage the block's weight slice: wt[ic][k][o] = wd[oc0+o][ic][k]
    for (int i = tid; i < CC * 144; i += 256) {
        int ic = i / 144;
        int rem = i - ic * 144;
        int k = rem >> 4, o = rem & 15;
        wt[ic][k][o] = wd[((size_t)(oc0 + o) * CC + ic) * 9 + k];
    }

    int   idx4[9][4];
    float wt4[9][4];
    const float* offb = off + (size_t)b * 18 * HWSZ + py * WW + px;
#pragma unroll
    for (int k = 0; k < 9; ++k) {
        float dyv = offb[(2 * k + 0) * HWSZ];
        float dxv = offb[(2 * k + 1) * HWSZ];
        float fy = (float)(py + k / 3 - 1) + dyv;
        float fx = (float)(px + k % 3 - 1) + dxv;
        float yl = floorf(fy), xl = floorf(fx);
        float ly = fy - yl, lx = fx - xl;
        int iy0 = (int)yl, ix0 = (int)xl;
        int iy1 = iy0 + 1, ix1 = ix0 + 1;
        float vy0 = (iy0 >= 0 && iy0 < HH) ? 1.f : 0.f;
        float vy1 = (iy1 >= 0 && iy1 < HH) ? 1.f : 0.f;
        float vx0 = (ix0 >= 0 && ix0 < WW) ? 1.f : 0.f;
        float vx1 = (ix1 >= 0 && ix1 < WW) ? 1.f : 0.f;
        int iy0c = min(max(iy0, 0), HH - 1), iy1c = min(max(iy1, 0), HH - 1);
        int ix0c = min(max(ix0, 0), WW - 1), ix1c = min(max(ix1, 0), WW - 1);
        idx4[k][0] = iy0c * WW + ix0c;
        idx4[k][1] = iy0c * WW + ix1c;
        idx4[k][2] = iy1c * WW + ix0c;
        idx4[k][3] = iy1c * WW + ix1c;
        wt4[k][0] = (1.f - ly) * (1.f - lx) * vy0 * vx0;
        wt4[k][1] = (1.f - ly) * lx         * vy0 * vx1;
        wt4[k][2] = ly * (1.f - lx) * vy1 * vx0;
        wt4[k][3] = ly * lx         * vy1 * vx1;
    }

    float acc[16];
#pragma unroll
    for (int o = 0; o < 16; ++o) acc[o] = bd[oc0 + o];

    __syncthreads();   // weights staged

    const float* xb = x + (size_t)b * CC * HWSZ;
#pragma unroll 2
    for (int ic = 0; ic < CC; ++ic) {
        const float* xc = xb + ic * HWSZ;
        // all 9 taps' blends first (36 gathers issued as a batch)
        float s[9];
#pragma unroll
        for (int k = 0; k < 9; ++k) {
            float v =      wt4[k][0] * xc[idx4[k][0]];
            v = fmaf(wt4[k][1], xc[idx4[k][1]], v);
            v = fmaf(wt4[k][2], xc[idx4[k][2]], v);
            v = fmaf(wt4[k][3], xc[idx4[k][3]], v);
            s[k] = v;
        }
#pragma unroll
        for (int k = 0; k < 9; ++k) {
            const float4* wp = reinterpret_cast<const float4*>(&wt[ic][k][0]);
            float4 wa = wp[0], wb = wp[1], wc = wp[2], wdd = wp[3];   // broadcasts
            float wv[16] = {wa.x, wa.y, wa.z, wa.w, wb.x, wb.y, wb.z, wb.w,
                            wc.x, wc.y, wc.z, wc.w, wdd.x, wdd.y, wdd.z, wdd.w};
#pragma unroll
            for (int o = 0; o < 16; ++o)
                acc[o] = fmaf(s[k], wv[o], acc[o]);
        }
    }

    float* ob = dout + ((size_t)b * CC + oc0) * HWSZ + py * WW + px;
#pragma unroll
    for (int o = 0; o < 16; ++o)
        ob[o * HWSZ] = acc[o];
}

// mean/var -> (scale, shift) per channel
__global__ void bnstat_k(const float* __restrict__ ssum, const float* __restrict__ ssq,
                         const float* __restrict__ g, const float* __restrict__ bet,
                         float* __restrict__ scale, float* __restrict__ shift)
{
    int c = threadIdx.x;
    const float invn = 1.f / (4.f * HWSZ);
    float mean = ssum[c] * invn;
    float var  = ssq[c] * invn - mean * mean;
    float sc = g[c] * rsqrtf(var + 1e-5f);
    scale[c] = sc;
    shift[c] = fmaf(-mean, sc, bet[c]);
}

// out = relu(dout + bn2(y2)), vectorized float4
__global__ __launch_bounds__(256)
void final_k(const float* __restrict__ dout, const float* __restrict__ y2,
             const float* __restrict__ scale, const float* __restrict__ shift,
             float* __restrict__ out)
{
    int i = blockIdx.x * 256 + threadIdx.x;       // over 2M/4 float4s
    int c = (i >> 10) & 127;                      // channel of this float4
    float4 d = reinterpret_cast<const float4*>(dout)[i];
    float4 y = reinterpret_cast<const float4*>(y2)[i];
    float sc = scale[c], sh = shift[c];
    float4 r;
    r.x = fmaxf(d.x + fmaf(y.x, sc, sh), 0.f);
    r.y = fmaxf(d.y + fmaf(y.y, sc, sh), 0.f);
    r.z = fmaxf(d.z + fmaf(y.z, sc, sh), 0.f);
    r.w = fmaxf(d.w + fmaf(y.w, sc, sh), 0.f);
    reinterpret_cast<float4*>(out)[i] = r;
}

extern "C" void kernel_launch(void* const* d_in, const int* in_sizes, int n_in,
                              void* d_out, int out_size, void* d_ws, size_t ws_size,
                              hipStream_t stream)
{
    const float* x     = (const float*)d_in[0];
    const float* w_off = (const float*)d_in[1];
    const float* b_off = (const float*)d_in[2];
    const float* w_d   = (const float*)d_in[3];
    const float* b_d   = (const float*)d_in[4];
    const float* w1    = (const float*)d_in[5];
    const float* b1    = (const float*)d_in[6];
    const float* g1    = (const float*)d_in[7];
    const float* be1   = (const float*)d_in[8];
    const float* w2    = (const float*)d_in[9];
    const float* b2    = (const float*)d_in[10];
    const float* g2    = (const float*)d_in[11];
    const float* be2   = (const float*)d_in[12];

    float* ws      = (float*)d_ws;
    float* off_buf = ws;                      // B*18*H*W       = 294912
    float* y1      = off_buf + 294912;        // B*C*H*W        = 2097152
    float* y2      = y1 + 2097152;
    float* dob     = y2 + 2097152;
    float* st      = dob + 2097152;           // stats/params
    // st: sum1[128] sq1[128] sum2[128] sq2[128] scale1[128] shift1[128] scale2[128] shift2[128]

    hipMemsetAsync(off_buf, 0, 294912 * sizeof(float), stream);
    hipMemsetAsync(st, 0, 512 * sizeof(float), stream);

    // offset conv: 18 oc (5 groups of 4), ic-split 4, atomic accumulate
    conv_k<0, false, false, true><<<dim3(2, 2, 4 * 5 * 4), 256, 0, stream>>>(
        x, w_off, b_off, nullptr, nullptr, off_buf, nullptr, nullptr, 18, 5, 4);

    // deformable conv -> dob
    dconv_k<<<dim3(4, 4, 32), 256, 0, stream>>>(x, off_buf, w_d, b_d, dob);

    // conv1 (+ BN1 stats) -> y1
    conv_k<1, false, true, false><<<dim3(2, 2, 4 * 32), 256, 0, stream>>>(
        x, w1, b1, nullptr, nullptr, y1, st, st + 128, 128, 32, 1);
    bnstat_k<<<1, 128, 0, stream>>>(st, st + 128, g1, be1, st + 512, st + 640);

    // conv2 on relu(bn1(y1)) fused into staging (+ BN2 stats) -> y2
    conv_k<2, true, true, false><<<dim3(2, 2, 4 * 32), 256, 0, stream>>>(
        y1, w2, b2, st + 512, st + 640, y2, st + 256, st + 384, 128, 32, 1);
    bnstat_k<<<1, 128, 0, stream>>>(st + 256, st + 384, g2, be2, st + 768, st + 896);

    // out = relu(dob + bn2(y2))
    final_k<<<dim3(2048), 256, 0, stream>>>(dob, y2, st + 768, st + 896, (float*)d_out);
}

// Round 7
// 731.436 us; speedup vs baseline: 2.4420x; 2.4420x over previous
//
#include <hip/hip_runtime.h>

#define HH 64
#define WW 64
#define CC 128
#define HWSZ 4096   // 64*64

typedef __attribute__((ext_vector_type(8))) short short8v;   // 8 bf16 (4 VGPRs)
typedef __attribute__((ext_vector_type(4))) float floatx4;   // MFMA acc

__device__ __forceinline__ unsigned short f2bf(float f) {
    unsigned u = __float_as_uint(f);
    return (unsigned short)((u + 0x7FFFu + ((u >> 16) & 1u)) >> 16);   // RNE
}
__device__ __forceinline__ float bf2f(unsigned short h) {
    return __uint_as_float(((unsigned)h) << 16);
}

// ---------------------------------------------------------------------------
// Pre-split conv weights w[oc][128][9] (f32) into the GEMM B blob:
// blob[kc=36][plane(hi/lo)][OCP][40] bf16, kr<32 valid (k = kc*32+kr, flat
// k = ic*9+kk).  Row pad to 40 shorts (80 B) keeps ds_read_b128 2-way-free.
// ---------------------------------------------------------------------------
__global__ void prepack_k(const float* __restrict__ w, unsigned short* __restrict__ blob,
                          int oc_total, int OCP)
{
    int i = blockIdx.x * 256 + threadIdx.x;
    if (i >= 36 * OCP * 32) return;
    int kr = i & 31;
    int rest = i >> 5;
    int oc = rest % OCP;
    int kc = rest / OCP;
    int k = kc * 32 + kr;
    float v = 0.f;
    if (oc < oc_total) v = w[((size_t)oc * CC + k / 9) * 9 + (k % 9)];
    unsigned short h = f2bf(v);
    unsigned short l = f2bf(v - bf2f(h));
    size_t base = (size_t)(kc * 2) * OCP * 40;
    blob[base + (size_t)oc * 40 + kr] = h;                    // plane 0 (hi)
    blob[base + (size_t)(OCP + oc) * 40 + kr] = l;            // plane 1 (lo)
}

// ---------------------------------------------------------------------------
// Implicit-GEMM 3x3 conv via MFMA, bf16-split for fp32-level precision:
// D = Ah*Bh + Ah*Bl + Al*Bh  (lo*lo negligible).
// M-tile = 64 px (one image row), N = OCP (128 or 32-padded-18), K = 1152
// in 36 chunks of 32.  A staged on the fly (im2col + optional BN+relu fused),
// B copied from the prepacked blob.  mfma_f32_16x16x32_bf16:
//   A-frag: lane holds A[m=lane&15][k=(lane>>4)*8 + j]
//   B-frag: lane holds B[k=(lane>>4)*8 + j][n=lane&15]
//   C/D   : col = lane&15 (n), row = (lane>>4)*4 + reg (m)  [guide m89]
// Epilogue: bias add, NCHW store (4 consecutive px -> dwordx4), optional
// per-channel sum/sumsq stats (shfl_xor 16/32 reduce + atomics).
// ---------------------------------------------------------------------------
template<int TAG, int OCP, int MFR, int NFR, int WM, bool BN_IN, bool STATS>
__global__ __launch_bounds__(256)
void gemm_k(const float* __restrict__ in, const float* __restrict__ blobf,
            const float* __restrict__ bias,
            const float* __restrict__ bnscale, const float* __restrict__ bnshift,
            float* __restrict__ out, float* __restrict__ ssum, float* __restrict__ ssq,
            int oc_total)
{
    __shared__ __align__(16) unsigned short Al[2][64][40];    // 10.2 KB
    __shared__ __align__(16) unsigned short Bl[2][OCP][40];   // 20.5 KB @128
    const int tid = threadIdx.x;
    const int lane = tid & 63;
    const int wid = tid >> 6;
    const int b = blockIdx.x >> 6;       // image
    const int y = blockIdx.x & 63;       // output row
    const int wm = wid % WM;
    const int wn = wid / WM;
    const int m0 = wm * MFR * 16;        // wave's px base within the 64-row
    const int n0 = wn * NFR * 16;        // wave's oc base
    const int lrow = lane & 15;
    const int lkg  = (lane >> 4) * 8;

    floatx4 acc[MFR][NFR];
#pragma unroll
    for (int mi = 0; mi < MFR; ++mi)
#pragma unroll
        for (int nj = 0; nj < NFR; ++nj)
            acc[mi][nj] = {0.f, 0.f, 0.f, 0.f};

    const unsigned short* blb = (const unsigned short*)blobf;
    const float* inb = in + (size_t)b * CC * HWSZ;
    const int px = tid & 63;             // staging role: this thread's column
    const int kr0 = (tid >> 6) * 8;      // staging role: 8 consecutive k

    for (int kc = 0; kc < 36; ++kc) {
        __syncthreads();
        // ---- A stage: im2col 64px x 32k, split into hi/lo bf16 planes ----
        short8v vh, vl;
#pragma unroll
        for (int j = 0; j < 8; ++j) {
            int k = kc * 32 + kr0 + j;
            int ic = k / 9;
            int kk = k - ic * 9;
            int ky = kk / 3;
            int gy = y + ky - 1;
            int gx = px + (kk - ky * 3) - 1;
            float v = 0.f;
            if ((unsigned)gy < (unsigned)HH && (unsigned)gx < (unsigned)WW) {
                v = inb[(size_t)ic * HWSZ + gy * WW + gx];
                if (BN_IN) v = fmaxf(fmaf(v, bnscale[ic], bnshift[ic]), 0.f);
            }
            unsigned short h = f2bf(v);
            vh[j] = (short)h;
            vl[j] = (short)f2bf(v - bf2f(h));
        }
        *(short8v*)&Al[0][px][kr0] = vh;
        *(short8v*)&Al[1][px][kr0] = vl;
        // ---- B stage: copy this chunk's slab from the prepacked blob ----
        {
            const float4* src = (const float4*)(blb + (size_t)(kc * 2) * OCP * 40);
            float4* dst = (float4*)&Bl[0][0][0];
            const int n16 = (2 * OCP * 40) / 8;   // float4 count
            for (int i = tid; i < n16; i += 256) dst[i] = src[i];
        }
        __syncthreads();
        // ---- fragments + MFMA ----
        short8v af[2][MFR], bfr[2][NFR];
#pragma unroll
        for (int mi = 0; mi < MFR; ++mi) {
            af[0][mi] = *(const short8v*)&Al[0][m0 + mi * 16 + lrow][lkg];
            af[1][mi] = *(const short8v*)&Al[1][m0 + mi * 16 + lrow][lkg];
        }
#pragma unroll
        for (int nj = 0; nj < NFR; ++nj) {
            bfr[0][nj] = *(const short8v*)&Bl[0][n0 + nj * 16 + lrow][lkg];
            bfr[1][nj] = *(const short8v*)&Bl[1][n0 + nj * 16 + lrow][lkg];
        }
#pragma unroll
        for (int mi = 0; mi < MFR; ++mi)
#pragma unroll
            for (int nj = 0; nj < NFR; ++nj) {
                acc[mi][nj] = __builtin_amdgcn_mfma_f32_16x16x32_bf16(af[0][mi], bfr[0][nj], acc[mi][nj], 0, 0, 0);
                acc[mi][nj] = __builtin_amdgcn_mfma_f32_16x16x32_bf16(af[0][mi], bfr[1][nj], acc[mi][nj], 0, 0, 0);
                acc[mi][nj] = __builtin_amdgcn_mfma_f32_16x16x32_bf16(af[1][mi], bfr[0][nj], acc[mi][nj], 0, 0, 0);
            }
    }
    // ---- epilogue: bias, NCHW store, stats ----
#pragma unroll
    for (int nj = 0; nj < NFR; ++nj) {
        int oc = n0 + nj * 16 + lrow;
        float bv = (oc < oc_total) ? bias[oc] : 0.f;
        float s = 0.f, q = 0.f;
#pragma unroll
        for (int mi = 0; mi < MFR; ++mi) {
            floatx4 r = acc[mi][nj];
            r.x += bv; r.y += bv; r.z += bv; r.w += bv;
            if (oc < oc_total) {
                int pxq = m0 + mi * 16 + (lane >> 4) * 4;
                *(float4*)(out + ((size_t)b * oc_total + oc) * HWSZ + y * WW + pxq) =
                    make_float4(r.x, r.y, r.z, r.w);
            }
            if (STATS) {
                s += r.x + r.y + r.z + r.w;
                q += r.x * r.x + r.y * r.y + r.z * r.z + r.w * r.w;
            }
        }
        if (STATS) {
            s += __shfl_xor(s, 16); q += __shfl_xor(q, 16);
            s += __shfl_xor(s, 32); q += __shfl_xor(q, 32);
            if (lane < 16) { atomicAdd(&ssum[oc], s); atomicAdd(&ssq[oc], q); }
        }
    }
}

// ---------------------------------------------------------------------------
// Deformable 3x3 conv — EXACT R1 version (measured 380 us, zero bank
// conflicts): global gathers, validity-folded bilinear weights, weights via
// block-uniform s_load, 1 px x 16 oc per thread.
// ---------------------------------------------------------------------------
__global__ __launch_bounds__(256)
void dconv_k(const float* __restrict__ x, const float* __restrict__ off,
             const float* __restrict__ wd, const float* __restrict__ bd,
             float* __restrict__ dout)
{
    const int tid = threadIdx.x;
    const int tx = tid & 15, ty = tid >> 4;
    const int px = blockIdx.x * 16 + tx;
    const int py = blockIdx.y * 16 + ty;
    const int b = blockIdx.z >> 3;
    const int oc0 = (blockIdx.z & 7) * 16;

    int   idx4[9][4];
    float wt4[9][4];
    const float* offb = off + (size_t)b * 18 * HWSZ + py * WW + px;
#pragma unroll
    for (int k = 0; k < 9; ++k) {
        const int ky = k / 3 - 1, kx = k % 3 - 1;
        float dy = offb[(2 * k + 0) * HWSZ];
        float dx = offb[(2 * k + 1) * HWSZ];
        float fy = (float)(py + ky) + dy;
        float fx = (float)(px + kx) + dx;
        float yl = floorf(fy), xl = floorf(fx);
        float ly = fy - yl, lx = fx - xl;
        int iy0 = (int)yl, ix0 = (int)xl;
        int iy1 = iy0 + 1, ix1 = ix0 + 1;
        float vy0 = (iy0 >= 0 && iy0 < HH) ? 1.f : 0.f;
        float vy1 = (iy1 >= 0 && iy1 < HH) ? 1.f : 0.f;
        float vx0 = (ix0 >= 0 && ix0 < WW) ? 1.f : 0.f;
        float vx1 = (ix1 >= 0 && ix1 < WW) ? 1.f : 0.f;
        int iy0c = min(max(iy0, 0), HH - 1), iy1c = min(max(iy1, 0), HH - 1);
        int ix0c = min(max(ix0, 0), WW - 1), ix1c = min(max(ix1, 0), WW - 1);
        wt4[k][0] = (1.f - ly) * (1.f - lx) * vy0 * vx0;
        wt4[k][1] = (1.f - ly) * lx         * vy0 * vx1;
        wt4[k][2] = ly         * (1.f - lx) * vy1 * vx0;
        wt4[k][3] = ly         * lx         * vy1 * vx1;
        idx4[k][0] = iy0c * WW + ix0c;
        idx4[k][1] = iy0c * WW + ix1c;
        idx4[k][2] = iy1c * WW + ix0c;
        idx4[k][3] = iy1c * WW + ix1c;
    }

    float acc[16];
#pragma unroll
    for (int o = 0; o < 16; ++o) acc[o] = bd[oc0 + o];

    const float* xb = x + (size_t)b * CC * HWSZ;
    for (int ic = 0; ic < CC; ++ic) {
        const float* xc = xb + ic * HWSZ;
        const float* wp = wd + ((size_t)oc0 * CC + ic) * 9;   // uniform -> s_load
#pragma unroll
        for (int k = 0; k < 9; ++k) {
            float s =      wt4[k][0] * xc[idx4[k][0]];
            s = fmaf(wt4[k][1], xc[idx4[k][1]], s);
            s = fmaf(wt4[k][2], xc[idx4[k][2]], s);
            s = fmaf(wt4[k][3], xc[idx4[k][3]], s);
#pragma unroll
            for (int o = 0; o < 16; ++o)
                acc[o] = fmaf(s, wp[o * CC * 9 + k], acc[o]);
        }
    }

    float* ob = dout + ((size_t)b * CC + oc0) * HWSZ + py * WW + px;
#pragma unroll
    for (int o = 0; o < 16; ++o)
        ob[o * HWSZ] = acc[o];
}

// mean/var -> (scale, shift) per channel
__global__ void bnstat_k(const float* __restrict__ ssum, const float* __restrict__ ssq,
                         const float* __restrict__ g, const float* __restrict__ bet,
                         float* __restrict__ scale, float* __restrict__ shift)
{
    int c = threadIdx.x;
    const float invn = 1.f / (4.f * HWSZ);
    float mean = ssum[c] * invn;
    float var  = ssq[c] * invn - mean * mean;
    float sc = g[c] * rsqrtf(var + 1e-5f);
    scale[c] = sc;
    shift[c] = fmaf(-mean, sc, bet[c]);
}

// out = relu(dout + bn2(y2)), vectorized float4 (all NCHW)
__global__ __launch_bounds__(256)
void final_k(const float* __restrict__ dout, const float* __restrict__ y2,
             const float* __restrict__ scale, const float* __restrict__ shift,
             float* __restrict__ out)
{
    int i = blockIdx.x * 256 + threadIdx.x;       // over 2M/4 float4s
    int c = (i >> 10) & 127;
    float4 d = reinterpret_cast<const float4*>(dout)[i];
    float4 yv = reinterpret_cast<const float4*>(y2)[i];
    float sc = scale[c], sh = shift[c];
    float4 r;
    r.x = fmaxf(d.x + fmaf(yv.x, sc, sh), 0.f);
    r.y = fmaxf(d.y + fmaf(yv.y, sc, sh), 0.f);
    r.z = fmaxf(d.z + fmaf(yv.z, sc, sh), 0.f);
    r.w = fmaxf(d.w + fmaf(yv.w, sc, sh), 0.f);
    reinterpret_cast<float4*>(out)[i] = r;
}

extern "C" void kernel_launch(void* const* d_in, const int* in_sizes, int n_in,
                              void* d_out, int out_size, void* d_ws, size_t ws_size,
                              hipStream_t stream)
{
    const float* x     = (const float*)d_in[0];
    const float* w_off = (const float*)d_in[1];
    const float* b_off = (const float*)d_in[2];
    const float* w_d   = (const float*)d_in[3];
    const float* b_d   = (const float*)d_in[4];
    const float* w1    = (const float*)d_in[5];
    const float* b1    = (const float*)d_in[6];
    const float* g1    = (const float*)d_in[7];
    const float* be1   = (const float*)d_in[8];
    const float* w2    = (const float*)d_in[9];
    const float* b2    = (const float*)d_in[10];
    const float* g2    = (const float*)d_in[11];
    const float* be2   = (const float*)d_in[12];

    float* ws      = (float*)d_ws;
    float* off_buf = ws;                       // 294912
    float* y1      = off_buf + 294912;         // 2097152
    float* y2      = y1 + 2097152;
    float* dob     = y2 + 2097152;
    float* wo_blob = dob + 2097152;            // 36*2*32*40 shorts = 46080 f
    float* w1_blob = wo_blob + 46080;          // 36*2*128*40 shorts = 184320 f
    float* w2_blob = w1_blob + 184320;
    float* st      = w2_blob + 184320;         // 1024 floats
    // st: sum1[128] sq1[128] sum2[128] sq2[128] scale1[128] shift1[128] scale2[128] shift2[128]

    hipMemsetAsync(st, 0, 512 * sizeof(float), stream);

    // pre-split weights into GEMM B blobs
    prepack_k<<<(36 * 32 * 32 + 255) / 256, 256, 0, stream>>>(w_off, (unsigned short*)wo_blob, 18, 32);
    prepack_k<<<(36 * 128 * 32 + 255) / 256, 256, 0, stream>>>(w1, (unsigned short*)w1_blob, 128, 128);
    prepack_k<<<(36 * 128 * 32 + 255) / 256, 256, 0, stream>>>(w2, (unsigned short*)w2_blob, 128, 128);

    // offset conv: N=32 (18 used), 4 waves stacked on M
    gemm_k<0, 32, 1, 2, 4, false, false><<<256, 256, 0, stream>>>(
        x, wo_blob, b_off, nullptr, nullptr, off_buf, nullptr, nullptr, 18);

    // deformable conv (R1 proven kernel) -> dob
    dconv_k<<<dim3(4, 4, 32), 256, 0, stream>>>(x, off_buf, w_d, b_d, dob);

    // conv1 + BN1 stats -> y1
    gemm_k<1, 128, 2, 4, 2, false, true><<<256, 256, 0, stream>>>(
        x, w1_blob, b1, nullptr, nullptr, y1, st, st + 128, 128);
    bnstat_k<<<1, 128, 0, stream>>>(st, st + 128, g1, be1, st + 512, st + 640);

    // conv2 on relu(bn1(y1)) fused into A-staging + BN2 stats -> y2
    gemm_k<2, 128, 2, 4, 2, true, true><<<256, 256, 0, stream>>>(
        y1, w2_blob, b2, st + 512, st + 640, y2, st + 256, st + 384, 128);
    bnstat_k<<<1, 128, 0, stream>>>(st + 256, st + 384, g2, be2, st + 768, st + 896);

    // out = relu(dob + bn2(y2))
    final_k<<<dim3(2048), 256, 0, stream>>>(dob, y2, st + 768, st + 896, (float*)d_out);
}

// Round 9
// 453.427 us; speedup vs baseline: 3.9393x; 1.6131x over previous
//
#include <hip/hip_runtime.h>

#define HH 64
#define WW 64
#define CC 128
#define HWSZ 4096   // 64*64

typedef __attribute__((ext_vector_type(8))) short short8v;   // 8 bf16 (4 VGPRs)
typedef __attribute__((ext_vector_type(4))) short short4v;
typedef __attribute__((ext_vector_type(4))) float floatx4;   // MFMA acc

__device__ __forceinline__ unsigned short f2bf(float f) {
    unsigned u = __float_as_uint(f);
    return (unsigned short)((u + 0x7FFFu + ((u >> 16) & 1u)) >> 16);   // RNE
}
__device__ __forceinline__ float bf2f(unsigned short h) {
    return __uint_as_float(((unsigned)h) << 16);
}

// ---------------------------------------------------------------------------
// Pre-split conv weights w[oc][128][9] (f32) into the GEMM B blob:
// blob[kc=36][plane(hi/lo)][OCP][40] bf16, kr<32 valid (k = kc*32+kr, flat
// k = ic*9+kk).  Row pad to 40 shorts (80 B) keeps ds_read_b128 2-way-free.
// ---------------------------------------------------------------------------
__global__ void prepack_k(const float* __restrict__ w, unsigned short* __restrict__ blob,
                          int oc_total, int OCP)
{
    int i = blockIdx.x * 256 + threadIdx.x;
    if (i >= 36 * OCP * 32) return;
    int kr = i & 31;
    int rest = i >> 5;
    int oc = rest % OCP;
    int kc = rest / OCP;
    int k = kc * 32 + kr;
    float v = 0.f;
    if (oc < oc_total) v = w[((size_t)oc * CC + k / 9) * 9 + (k % 9)];
    unsigned short h = f2bf(v);
    unsigned short l = f2bf(v - bf2f(h));
    size_t base = (size_t)(kc * 2) * OCP * 40;
    blob[base + (size_t)oc * 40 + kr] = h;                    // plane 0 (hi)
    blob[base + (size_t)(OCP + oc) * 40 + kr] = l;            // plane 1 (lo)
}

// ---------------------------------------------------------------------------
// Implicit-GEMM 3x3 conv via MFMA, bf16-split for fp32-level precision:
// D = Ah*Bh + Ah*Bl + Al*Bh  (lo*lo negligible).  (Unchanged from R7.)
// ---------------------------------------------------------------------------
template<int TAG, int OCP, int MFR, int NFR, int WM, bool BN_IN, bool STATS>
__global__ __launch_bounds__(256)
void gemm_k(const float* __restrict__ in, const float* __restrict__ blobf,
            const float* __restrict__ bias,
            const float* __restrict__ bnscale, const float* __restrict__ bnshift,
            float* __restrict__ out, float* __restrict__ ssum, float* __restrict__ ssq,
            int oc_total)
{
    __shared__ __align__(16) unsigned short Al[2][64][40];
    __shared__ __align__(16) unsigned short Bl[2][OCP][40];
    const int tid = threadIdx.x;
    const int lane = tid & 63;
    const int wid = tid >> 6;
    const int b = blockIdx.x >> 6;
    const int y = blockIdx.x & 63;
    const int wm = wid % WM;
    const int wn = wid / WM;
    const int m0 = wm * MFR * 16;
    const int n0 = wn * NFR * 16;
    const int lrow = lane & 15;
    const int lkg  = (lane >> 4) * 8;

    floatx4 acc[MFR][NFR];
#pragma unroll
    for (int mi = 0; mi < MFR; ++mi)
#pragma unroll
        for (int nj = 0; nj < NFR; ++nj)
            acc[mi][nj] = {0.f, 0.f, 0.f, 0.f};

    const unsigned short* blb = (const unsigned short*)blobf;
    const float* inb = in + (size_t)b * CC * HWSZ;
    const int px = tid & 63;
    const int kr0 = (tid >> 6) * 8;

    for (int kc = 0; kc < 36; ++kc) {
        __syncthreads();
        short8v vh, vl;
#pragma unroll
        for (int j = 0; j < 8; ++j) {
            int k = kc * 32 + kr0 + j;
            int ic = k / 9;
            int kk = k - ic * 9;
            int ky = kk / 3;
            int gy = y + ky - 1;
            int gx = px + (kk - ky * 3) - 1;
            float v = 0.f;
            if ((unsigned)gy < (unsigned)HH && (unsigned)gx < (unsigned)WW) {
                v = inb[(size_t)ic * HWSZ + gy * WW + gx];
                if (BN_IN) v = fmaxf(fmaf(v, bnscale[ic], bnshift[ic]), 0.f);
            }
            unsigned short h = f2bf(v);
            vh[j] = (short)h;
            vl[j] = (short)f2bf(v - bf2f(h));
        }
        *(short8v*)&Al[0][px][kr0] = vh;
        *(short8v*)&Al[1][px][kr0] = vl;
        {
            const float4* src = (const float4*)(blb + (size_t)(kc * 2) * OCP * 40);
            float4* dst = (float4*)&Bl[0][0][0];
            const int n16 = (2 * OCP * 40) / 8;
            for (int i = tid; i < n16; i += 256) dst[i] = src[i];
        }
        __syncthreads();
        short8v af[2][MFR], bfr[2][NFR];
#pragma unroll
        for (int mi = 0; mi < MFR; ++mi) {
            af[0][mi] = *(const short8v*)&Al[0][m0 + mi * 16 + lrow][lkg];
            af[1][mi] = *(const short8v*)&Al[1][m0 + mi * 16 + lrow][lkg];
        }
#pragma unroll
        for (int nj = 0; nj < NFR; ++nj) {
            bfr[0][nj] = *(const short8v*)&Bl[0][n0 + nj * 16 + lrow][lkg];
            bfr[1][nj] = *(const short8v*)&Bl[1][n0 + nj * 16 + lrow][lkg];
        }
#pragma unroll
        for (int mi = 0; mi < MFR; ++mi)
#pragma unroll
            for (int nj = 0; nj < NFR; ++nj) {
                acc[mi][nj] = __builtin_amdgcn_mfma_f32_16x16x32_bf16(af[0][mi], bfr[0][nj], acc[mi][nj], 0, 0, 0);
                acc[mi][nj] = __builtin_amdgcn_mfma_f32_16x16x32_bf16(af[0][mi], bfr[1][nj], acc[mi][nj], 0, 0, 0);
                acc[mi][nj] = __builtin_amdgcn_mfma_f32_16x16x32_bf16(af[1][mi], bfr[0][nj], acc[mi][nj], 0, 0, 0);
            }
    }
#pragma unroll
    for (int nj = 0; nj < NFR; ++nj) {
        int oc = n0 + nj * 16 + lrow;
        float bv = (oc < oc_total) ? bias[oc] : 0.f;
        float s = 0.f, q = 0.f;
#pragma unroll
        for (int mi = 0; mi < MFR; ++mi) {
            floatx4 r = acc[mi][nj];
            r.x += bv; r.y += bv; r.z += bv; r.w += bv;
            if (oc < oc_total) {
                int pxq = m0 + mi * 16 + (lane >> 4) * 4;
                *(float4*)(out + ((size_t)b * oc_total + oc) * HWSZ + y * WW + pxq) =
                    make_float4(r.x, r.y, r.z, r.w);
            }
            if (STATS) {
                s += r.x + r.y + r.z + r.w;
                q += r.x * r.x + r.y * r.y + r.z * r.z + r.w * r.w;
            }
        }
        if (STATS) {
            s += __shfl_xor(s, 16); q += __shfl_xor(q, 16);
            s += __shfl_xor(s, 32); q += __shfl_xor(q, 32);
            if (lane < 16) { atomicAdd(&ssum[oc], s); atomicAdd(&ssq[oc], q); }
        }
    }
}

// ---------------------------------------------------------------------------
// Deformable conv as implicit GEMM with bilinear sampling fused into the
// A-staging.  Each sampled value is computed ONCE (all 128 oc in-block,
// vs 8x redundant gathers in the old per-oc-group scalar kernel).
// Block: 512 threads (8 waves: 2M x 4N), M = 64 px (one image row),
// N = 128 oc, K = 1152 in 36 chunks of 32.
// Per-block precompute: 9 taps x 64 px -> {4 corner idx, 4 validity-folded
// bilinear weights} in LDS (18.4 KB).  A-stage: per k-element, 2 LDS b128
// tap reads + 4 near-coalesced global gathers + blend + bf16 hi/lo split.
// B: prepacked w_d blob.  Same triple-MFMA bf16-split as gemm_k.
// ---------------------------------------------------------------------------
__global__ __launch_bounds__(512)
void dgemm_k(const float* __restrict__ x, const float* __restrict__ off,
             const float* __restrict__ blobf, const float* __restrict__ bd,
             float* __restrict__ dout)
{
    __shared__ __align__(16) unsigned short Al[2][64][40];    // 10.2 KB
    __shared__ __align__(16) unsigned short Bl[2][CC][40];    // 20.5 KB
    __shared__ __align__(16) float tw[9][64][4];              // 9.2 KB
    __shared__ __align__(16) int   ti[9][64][4];              // 9.2 KB
    const int tid = threadIdx.x;
    const int lane = tid & 63;
    const int wid = tid >> 6;            // 0..7
    const int b = blockIdx.x >> 6;       // image
    const int y = blockIdx.x & 63;       // output row
    const int wm = wid & 1;
    const int wn = wid >> 1;             // 0..3
    const int m0 = wm * 32;              // MFR=2
    const int n0 = wn * 32;              // NFR=2
    const int lrow = lane & 15;
    const int lkg  = (lane >> 4) * 8;

    // ---- precompute taps: idx4 + validity-folded bilinear weights ----
    for (int e = tid; e < 9 * 64; e += 512) {
        int kk = e >> 6, px = e & 63;
        const float* ob = off + (size_t)b * 18 * HWSZ + y * WW + px;
        float dyv = ob[(2 * kk + 0) * HWSZ];
        float dxv = ob[(2 * kk + 1) * HWSZ];
        float fy = (float)(y + kk / 3 - 1) + dyv;
        float fx = (float)(px + kk % 3 - 1) + dxv;
        float yl = floorf(fy), xl = floorf(fx);
        float ly = fy - yl, lx = fx - xl;
        int iy0 = (int)yl, ix0 = (int)xl;
        int iy1 = iy0 + 1, ix1 = ix0 + 1;
        float vy0 = (iy0 >= 0 && iy0 < HH) ? 1.f : 0.f;
        float vy1 = (iy1 >= 0 && iy1 < HH) ? 1.f : 0.f;
        float vx0 = (ix0 >= 0 && ix0 < WW) ? 1.f : 0.f;
        float vx1 = (ix1 >= 0 && ix1 < WW) ? 1.f : 0.f;
        int iy0c = min(max(iy0, 0), HH - 1), iy1c = min(max(iy1, 0), HH - 1);
        int ix0c = min(max(ix0, 0), WW - 1), ix1c = min(max(ix1, 0), WW - 1);
        ti[kk][px][0] = iy0c * WW + ix0c;
        ti[kk][px][1] = iy0c * WW + ix1c;
        ti[kk][px][2] = iy1c * WW + ix0c;
        ti[kk][px][3] = iy1c * WW + ix1c;
        tw[kk][px][0] = (1.f - ly) * (1.f - lx) * vy0 * vx0;
        tw[kk][px][1] = (1.f - ly) * lx         * vy0 * vx1;
        tw[kk][px][2] = ly * (1.f - lx) * vy1 * vx0;
        tw[kk][px][3] = ly * lx         * vy1 * vx1;
    }

    floatx4 acc[2][2];
#pragma unroll
    for (int mi = 0; mi < 2; ++mi)
#pragma unroll
        for (int nj = 0; nj < 2; ++nj)
            acc[mi][nj] = {0.f, 0.f, 0.f, 0.f};

    const unsigned short* blb = (const unsigned short*)blobf;
    const float* xb = x + (size_t)b * CC * HWSZ;
    const int px = tid & 63;
    const int kr0 = (tid >> 6) * 4;      // 4 k-elements per thread (512 thr)

    for (int kc = 0; kc < 36; ++kc) {
        __syncthreads();   // guards Al/Bl reuse; first iter fences tap precompute
        // ---- A stage: sampled im2col, 64px x 32k, hi/lo split ----
        short4v vh, vl;
#pragma unroll
        for (int j = 0; j < 4; ++j) {
            int k = kc * 32 + kr0 + j;   // wave-uniform
            int ic = k / 9;
            int kk = k - ic * 9;
            const float* xc = xb + (size_t)ic * HWSZ;
            float4 w4 = *(const float4*)&tw[kk][px][0];
            int4   i4 = *(const int4*)&ti[kk][px][0];
            float v =      w4.x * xc[i4.x];
            v = fmaf(w4.y, xc[i4.y], v);
            v = fmaf(w4.z, xc[i4.z], v);
            v = fmaf(w4.w, xc[i4.w], v);
            unsigned short h = f2bf(v);
            vh[j] = (short)h;
            vl[j] = (short)f2bf(v - bf2f(h));
        }
        *(short4v*)&Al[0][px][kr0] = vh;
        *(short4v*)&Al[1][px][kr0] = vl;
        // ---- B stage: copy chunk slab ----
        {
            const float4* src = (const float4*)(blb + (size_t)(kc * 2) * CC * 40);
            float4* dst = (float4*)&Bl[0][0][0];
            const int n16 = (2 * CC * 40) / 8;
            for (int i = tid; i < n16; i += 512) dst[i] = src[i];
        }
        __syncthreads();
        // ---- fragments + MFMA ----
        short8v af[2][2], bfr[2][2];
#pragma unroll
        for (int mi = 0; mi < 2; ++mi) {
            af[0][mi] = *(const short8v*)&Al[0][m0 + mi * 16 + lrow][lkg];
            af[1][mi] = *(const short8v*)&Al[1][m0 + mi * 16 + lrow][lkg];
        }
#pragma unroll
        for (int nj = 0; nj < 2; ++nj) {
            bfr[0][nj] = *(const short8v*)&Bl[0][n0 + nj * 16 + lrow][lkg];
            bfr[1][nj] = *(const short8v*)&Bl[1][n0 + nj * 16 + lrow][lkg];
        }
#pragma unroll
        for (int mi = 0; mi < 2; ++mi)
#pragma unroll
            for (int nj = 0; nj < 2; ++nj) {
                acc[mi][nj] = __builtin_amdgcn_mfma_f32_16x16x32_bf16(af[0][mi], bfr[0][nj], acc[mi][nj], 0, 0, 0);
                acc[mi][nj] = __builtin_amdgcn_mfma_f32_16x16x32_bf16(af[0][mi], bfr[1][nj], acc[mi][nj], 0, 0, 0);
                acc[mi][nj] = __builtin_amdgcn_mfma_f32_16x16x32_bf16(af[1][mi], bfr[0][nj], acc[mi][nj], 0, 0, 0);
            }
    }
    // ---- epilogue: bias + NCHW store ----
#pragma unroll
    for (int nj = 0; nj < 2; ++nj) {
        int oc = n0 + nj * 16 + lrow;
        float bv = bd[oc];
#pragma unroll
        for (int mi = 0; mi < 2; ++mi) {
            floatx4 r = acc[mi][nj];
            int pxq = m0 + mi * 16 + (lane >> 4) * 4;
            *(float4*)(dout + ((size_t)b * CC + oc) * HWSZ + y * WW + pxq) =
                make_float4(r.x + bv, r.y + bv, r.z + bv, r.w + bv);
        }
    }
}

// mean/var -> (scale, shift) per channel
__global__ void bnstat_k(const float* __restrict__ ssum, const float* __restrict__ ssq,
                         const float* __restrict__ g, const float* __restrict__ bet,
                         float* __restrict__ scale, float* __restrict__ shift)
{
    int c = threadIdx.x;
    const float invn = 1.f / (4.f * HWSZ);
    float mean = ssum[c] * invn;
    float var  = ssq[c] * invn - mean * mean;
    float sc = g[c] * rsqrtf(var + 1e-5f);
    scale[c] = sc;
    shift[c] = fmaf(-mean, sc, bet[c]);
}

// out = relu(dout + bn2(y2)), vectorized float4 (all NCHW)
__global__ __launch_bounds__(256)
void final_k(const float* __restrict__ dout, const float* __restrict__ y2,
             const float* __restrict__ scale, const float* __restrict__ shift,
             float* __restrict__ out)
{
    int i = blockIdx.x * 256 + threadIdx.x;
    int c = (i >> 10) & 127;
    float4 d = reinterpret_cast<const float4*>(dout)[i];
    float4 yv = reinterpret_cast<const float4*>(y2)[i];
    float sc = scale[c], sh = shift[c];
    float4 r;
    r.x = fmaxf(d.x + fmaf(yv.x, sc, sh), 0.f);
    r.y = fmaxf(d.y + fmaf(yv.y, sc, sh), 0.f);
    r.z = fmaxf(d.z + fmaf(yv.z, sc, sh), 0.f);
    r.w = fmaxf(d.w + fmaf(yv.w, sc, sh), 0.f);
    reinterpret_cast<float4*>(out)[i] = r;
}

extern "C" void kernel_launch(void* const* d_in, const int* in_sizes, int n_in,
                              void* d_out, int out_size, void* d_ws, size_t ws_size,
                              hipStream_t stream)
{
    const float* x     = (const float*)d_in[0];
    const float* w_off = (const float*)d_in[1];
    const float* b_off = (const float*)d_in[2];
    const float* w_d   = (const float*)d_in[3];
    const float* b_d   = (const float*)d_in[4];
    const float* w1    = (const float*)d_in[5];
    const float* b1    = (const float*)d_in[6];
    const float* g1    = (const float*)d_in[7];
    const float* be1   = (const float*)d_in[8];
    const float* w2    = (const float*)d_in[9];
    const float* b2    = (const float*)d_in[10];
    const float* g2    = (const float*)d_in[11];
    const float* be2   = (const float*)d_in[12];

    float* ws      = (float*)d_ws;
    float* off_buf = ws;                       // 294912
    float* y1      = off_buf + 294912;         // 2097152
    float* y2      = y1 + 2097152;
    float* dob     = y2 + 2097152;
    float* wo_blob = dob + 2097152;            // 36*2*32*40 shorts = 46080 f
    float* w1_blob = wo_blob + 46080;          // 36*2*128*40 shorts = 184320 f
    float* w2_blob = w1_blob + 184320;
    float* wd_blob = w2_blob + 184320;
    float* st      = wd_blob + 184320;         // 1024 floats
    // st: sum1[128] sq1[128] sum2[128] sq2[128] scale1[128] shift1[128] scale2[128] shift2[128]

    hipMemsetAsync(st, 0, 512 * sizeof(float), stream);

    // pre-split weights into GEMM B blobs
    prepack_k<<<(36 * 32 * 32 + 255) / 256, 256, 0, stream>>>(w_off, (unsigned short*)wo_blob, 18, 32);
    prepack_k<<<(36 * 128 * 32 + 255) / 256, 256, 0, stream>>>(w1, (unsigned short*)w1_blob, 128, 128);
    prepack_k<<<(36 * 128 * 32 + 255) / 256, 256, 0, stream>>>(w2, (unsigned short*)w2_blob, 128, 128);
    prepack_k<<<(36 * 128 * 32 + 255) / 256, 256, 0, stream>>>(w_d, (unsigned short*)wd_blob, 128, 128);

    // offset conv: N=32 (18 used), 4 waves stacked on M
    gemm_k<0, 32, 1, 2, 4, false, false><<<256, 256, 0, stream>>>(
        x, wo_blob, b_off, nullptr, nullptr, off_buf, nullptr, nullptr, 18);

    // deformable conv as sampled implicit GEMM -> dob
    dgemm_k<<<256, 512, 0, stream>>>(x, off_buf, wd_blob, b_d, dob);

    // conv1 + BN1 stats -> y1
    gemm_k<1, 128, 2, 4, 2, false, true><<<256, 256, 0, stream>>>(
        x, w1_blob, b1, nullptr, nullptr, y1, st, st + 128, 128);
    bnstat_k<<<1, 128, 0, stream>>>(st, st + 128, g1, be1, st + 512, st + 640);

    // conv2 on relu(bn1(y1)) fused into A-staging + BN2 stats -> y2
    gemm_k<2, 128, 2, 4, 2, true, true><<<256, 256, 0, stream>>>(
        y1, w2_blob, b2, st + 512, st + 640, y2, st + 256, st + 384, 128);
    bnstat_k<<<1, 128, 0, stream>>>(st + 256, st + 384, g2, be2, st + 768, st + 896);

    // out = relu(dob + bn2(y2))
    final_k<<<dim3(2048), 256, 0, stream>>>(dob, y2, st + 768, st + 896, (float*)d_out);
}

// Round 12
// 434.918 us; speedup vs baseline: 4.1069x; 1.0426x over previous
//
#include <hip/hip_runtime.h>

#define HH 64
#define WW 64
#define CC 128
#define HWSZ 4096   // 64*64

typedef __attribute__((ext_vector_type(8))) short short8v;   // 8 bf16 (4 VGPRs)
typedef __attribute__((ext_vector_type(4))) short short4v;
typedef __attribute__((ext_vector_type(4))) float floatx4;   // MFMA acc

__device__ __forceinline__ unsigned short f2bf(float f) {
    unsigned u = __float_as_uint(f);
    return (unsigned short)((u + 0x7FFFu + ((u >> 16) & 1u)) >> 16);   // RNE
}
__device__ __forceinline__ float bf2f(unsigned short h) {
    return __uint_as_float(((unsigned)h) << 16);
}

// ---------------------------------------------------------------------------
// Pre-split conv weights w[oc][128][9] (f32) into the GEMM B blob:
// blob[kc=36][plane(hi/lo)][OCP][40] bf16.  (Unchanged from R7.)
// ---------------------------------------------------------------------------
__global__ void prepack_k(const float* __restrict__ w, unsigned short* __restrict__ blob,
                          int oc_total, int OCP)
{
    int i = blockIdx.x * 256 + threadIdx.x;
    if (i >= 36 * OCP * 32) return;
    int kr = i & 31;
    int rest = i >> 5;
    int oc = rest % OCP;
    int kc = rest / OCP;
    int k = kc * 32 + kr;
    float v = 0.f;
    if (oc < oc_total) v = w[((size_t)oc * CC + k / 9) * 9 + (k % 9)];
    unsigned short h = f2bf(v);
    unsigned short l = f2bf(v - bf2f(h));
    size_t base = (size_t)(kc * 2) * OCP * 40;
    blob[base + (size_t)oc * 40 + kr] = h;
    blob[base + (size_t)(OCP + oc) * 40 + kr] = l;
}

// ---------------------------------------------------------------------------
// Implicit-GEMM 3x3 conv via MFMA, bf16-split, SOFTWARE-PIPELINED:
// double-buffered Al/Bl; kc+1's global loads are issued into REGISTERS
// before kc's MFMAs, and the dependent work (BN, bf16 split, ds_write)
// runs after them -- HBM/L2 latency hides under compute.  1 barrier/iter.
// THREADS=512 -> 8 waves (2M x 4N); THREADS=256 -> 4 waves.
// ---------------------------------------------------------------------------
template<int TAG, int OCP, int THREADS, int WM, int MFR, int NFR, bool BN_IN, bool STATS>
__global__ __launch_bounds__(THREADS)
void gemm_k(const float* __restrict__ in, const float* __restrict__ blobf,
            const float* __restrict__ bias,
            const float* __restrict__ bnscale, const float* __restrict__ bnshift,
            float* __restrict__ out, float* __restrict__ ssum, float* __restrict__ ssq,
            int oc_total)
{
    constexpr int KPT   = 2048 / THREADS;                 // A k-elems/thread
    constexpr int NB4   = OCP * 10;                       // B float4s per kc
    constexpr int NITER = (NB4 + THREADS - 1) / THREADS;
    __shared__ __align__(16) unsigned short Al[2][2][64][40];
    __shared__ __align__(16) unsigned short Bl[2][2][OCP][40];
    const int tid = threadIdx.x;
    const int lane = tid & 63;
    const int wid = tid >> 6;
    const int b = blockIdx.x >> 6;
    const int y = blockIdx.x & 63;
    const int wm = wid % WM;
    const int wn = wid / WM;
    const int m0 = wm * MFR * 16;
    const int n0 = wn * NFR * 16;
    const int lrow = lane & 15;
    const int lkg  = (lane >> 4) * 8;

    floatx4 acc[MFR][NFR];
#pragma unroll
    for (int mi = 0; mi < MFR; ++mi)
#pragma unroll
        for (int nj = 0; nj < NFR; ++nj)
            acc[mi][nj] = {0.f, 0.f, 0.f, 0.f};

    const unsigned short* blb = (const unsigned short*)blobf;
    const float* inb = in + (size_t)b * CC * HWSZ;
    const int px = tid & 63;
    const int kr0 = (tid >> 6) * KPT;

    float  aval[KPT], asc[KPT], ash[KPT];
    float4 breg[NITER];

    auto load_stage = [&](int kc) {
#pragma unroll
        for (int j = 0; j < KPT; ++j) {
            int k = kc * 32 + kr0 + j;
            int ic = k / 9;
            int kk = k - ic * 9;
            int ky = kk / 3;
            int gy = y + ky - 1;
            int gx = px + (kk - ky * 3) - 1;
            aval[j] = ((unsigned)gy < (unsigned)HH && (unsigned)gx < (unsigned)WW)
                      ? inb[(size_t)ic * HWSZ + gy * WW + gx] : 0.f;
            if (BN_IN) { asc[j] = bnscale[ic]; ash[j] = bnshift[ic]; }
        }
        const float4* src = (const float4*)(blb + (size_t)(kc * 2) * OCP * 40);
#pragma unroll
        for (int t = 0; t < NITER; ++t) {
            int idx = tid + t * THREADS;
            if (idx < NB4) breg[t] = src[idx];
        }
    };
    auto write_stage = [&](int buf) {
        if constexpr (KPT == 4) {
            short4v vh, vl;
#pragma unroll
            for (int j = 0; j < 4; ++j) {
                float v = aval[j];
                if (BN_IN) v = fmaxf(fmaf(v, asc[j], ash[j]), 0.f);
                unsigned short h = f2bf(v);
                vh[j] = (short)h;
                vl[j] = (short)f2bf(v - bf2f(h));
            }
            *(short4v*)&Al[buf][0][px][kr0] = vh;
            *(short4v*)&Al[buf][1][px][kr0] = vl;
        } else {
            short8v vh, vl;
#pragma unroll
            for (int j = 0; j < 8; ++j) {
                float v = aval[j];
                if (BN_IN) v = fmaxf(fmaf(v, asc[j], ash[j]), 0.f);
                unsigned short h = f2bf(v);
                vh[j] = (short)h;
                vl[j] = (short)f2bf(v - bf2f(h));
            }
            *(short8v*)&Al[buf][0][px][kr0] = vh;
            *(short8v*)&Al[buf][1][px][kr0] = vl;
        }
        float4* dst = (float4*)&Bl[buf][0][0][0];
#pragma unroll
        for (int t = 0; t < NITER; ++t) {
            int idx = tid + t * THREADS;
            if (idx < NB4) dst[idx] = breg[t];
        }
    };

    load_stage(0);
    write_stage(0);
    __syncthreads();

    for (int kc = 0; kc < 36; ++kc) {
        const int cur = kc & 1;
        if (kc < 35) load_stage(kc + 1);         // issue next-tile loads (regs)

        short8v af[2][MFR], bfr[2][NFR];
#pragma unroll
        for (int mi = 0; mi < MFR; ++mi) {
            af[0][mi] = *(const short8v*)&Al[cur][0][m0 + mi * 16 + lrow][lkg];
            af[1][mi] = *(const short8v*)&Al[cur][1][m0 + mi * 16 + lrow][lkg];
        }
#pragma unroll
        for (int nj = 0; nj < NFR; ++nj) {
            bfr[0][nj] = *(const short8v*)&Bl[cur][0][n0 + nj * 16 + lrow][lkg];
            bfr[1][nj] = *(const short8v*)&Bl[cur][1][n0 + nj * 16 + lrow][lkg];
        }
#pragma unroll
        for (int mi = 0; mi < MFR; ++mi)
#pragma unroll
            for (int nj = 0; nj < NFR; ++nj) {
                acc[mi][nj] = __builtin_amdgcn_mfma_f32_16x16x32_bf16(af[0][mi], bfr[0][nj], acc[mi][nj], 0, 0, 0);
                acc[mi][nj] = __builtin_amdgcn_mfma_f32_16x16x32_bf16(af[0][mi], bfr[1][nj], acc[mi][nj], 0, 0, 0);
                acc[mi][nj] = __builtin_amdgcn_mfma_f32_16x16x32_bf16(af[1][mi], bfr[0][nj], acc[mi][nj], 0, 0, 0);
            }

        if (kc < 35) write_stage(cur ^ 1);       // dependent math + ds_write
        __syncthreads();
    }

#pragma unroll
    for (int nj = 0; nj < NFR; ++nj) {
        int oc = n0 + nj * 16 + lrow;
        float bv = (oc < oc_total) ? bias[oc] : 0.f;
        float s = 0.f, q = 0.f;
#pragma unroll
        for (int mi = 0; mi < MFR; ++mi) {
            floatx4 r = acc[mi][nj];
            r.x += bv; r.y += bv; r.z += bv; r.w += bv;
            if (oc < oc_total) {
                int pxq = m0 + mi * 16 + (lane >> 4) * 4;
                *(float4*)(out + ((size_t)b * oc_total + oc) * HWSZ + y * WW + pxq) =
                    make_float4(r.x, r.y, r.z, r.w);
            }
            if (STATS) {
                s += r.x + r.y + r.z + r.w;
                q += r.x * r.x + r.y * r.y + r.z * r.z + r.w * r.w;
            }
        }
        if (STATS) {
            s += __shfl_xor(s, 16); q += __shfl_xor(q, 16);
            s += __shfl_xor(s, 32); q += __shfl_xor(q, 32);
            if (lane < 16) { atomicAdd(&ssum[oc], s); atomicAdd(&ssq[oc], q); }
        }
    }
}

// ---------------------------------------------------------------------------
// Deformable conv as sampled implicit GEMM, same software pipeline:
// gathers for kc+1 issue before kc's MFMAs; bilinear blend + split + ds_write
// after.  512 threads, 8 waves (2M x 4N), double-buffered Al/Bl.
// ---------------------------------------------------------------------------
__global__ __launch_bounds__(512)
void dgemm_k(const float* __restrict__ x, const float* __restrict__ off,
             const float* __restrict__ blobf, const float* __restrict__ bd,
             float* __restrict__ dout)
{
    constexpr int NITER = 3;                              // 1280 f4 / 512
    __shared__ __align__(16) unsigned short Al[2][2][64][40];
    __shared__ __align__(16) unsigned short Bl[2][2][CC][40];
    __shared__ __align__(16) float tw[9][64][4];
    __shared__ __align__(16) int   ti[9][64][4];
    const int tid = threadIdx.x;
    const int lane = tid & 63;
    const int wid = tid >> 6;
    const int b = blockIdx.x >> 6;
    const int y = blockIdx.x & 63;
    const int wm = wid & 1;
    const int wn = wid >> 1;
    const int m0 = wm * 32;
    const int n0 = wn * 32;
    const int lrow = lane & 15;
    const int lkg  = (lane >> 4) * 8;

    for (int e = tid; e < 9 * 64; e += 512) {
        int kk = e >> 6, px = e & 63;
        const float* ob = off + (size_t)b * 18 * HWSZ + y * WW + px;
        float dyv = ob[(2 * kk + 0) * HWSZ];
        float dxv = ob[(2 * kk + 1) * HWSZ];
        float fy = (float)(y + kk / 3 - 1) + dyv;
        float fx = (float)(px + kk % 3 - 1) + dxv;
        float yl = floorf(fy), xl = floorf(fx);
        float ly = fy - yl, lx = fx - xl;
        int iy0 = (int)yl, ix0 = (int)xl;
        int iy1 = iy0 + 1, ix1 = ix0 + 1;
        float vy0 = (iy0 >= 0 && iy0 < HH) ? 1.f : 0.f;
        float vy1 = (iy1 >= 0 && iy1 < HH) ? 1.f : 0.f;
        float vx0 = (ix0 >= 0 && ix0 < WW) ? 1.f : 0.f;
        float vx1 = (ix1 >= 0 && ix1 < WW) ? 1.f : 0.f;
        int iy0c = min(max(iy0, 0), HH - 1), iy1c = min(max(iy1, 0), HH - 1);
        int ix0c = min(max(ix0, 0), WW - 1), ix1c = min(max(ix1, 0), WW - 1);
        ti[kk][px][0] = iy0c * WW + ix0c;
        ti[kk][px][1] = iy0c * WW + ix1c;
        ti[kk][px][2] = iy1c * WW + ix0c;
        ti[kk][px][3] = iy1c * WW + ix1c;
        tw[kk][px][0] = (1.f - ly) * (1.f - lx) * vy0 * vx0;
        tw[kk][px][1] = (1.f - ly) * lx         * vy0 * vx1;
        tw[kk][px][2] = ly * (1.f - lx) * vy1 * vx0;
        tw[kk][px][3] = ly * lx         * vy1 * vx1;
    }

    floatx4 acc[2][2];
#pragma unroll
    for (int mi = 0; mi < 2; ++mi)
#pragma unroll
        for (int nj = 0; nj < 2; ++nj)
            acc[mi][nj] = {0.f, 0.f, 0.f, 0.f};

    const unsigned short* blb = (const unsigned short*)blobf;
    const float* xb = x + (size_t)b * CC * HWSZ;
    const int px = tid & 63;
    const int kr0 = (tid >> 6) * 4;

    float  g4[4][4];
    float4 breg[NITER];

    auto load_stage = [&](int kc) {
#pragma unroll
        for (int j = 0; j < 4; ++j) {
            int k = kc * 32 + kr0 + j;
            int ic = k / 9;
            int kk = k - ic * 9;
            const float* xc = xb + (size_t)ic * HWSZ;
            int4 i4 = *(const int4*)&ti[kk][px][0];
            g4[j][0] = xc[i4.x];
            g4[j][1] = xc[i4.y];
            g4[j][2] = xc[i4.z];
            g4[j][3] = xc[i4.w];
        }
        const float4* src = (const float4*)(blb + (size_t)(kc * 2) * CC * 40);
#pragma unroll
        for (int t = 0; t < NITER; ++t) {
            int idx = tid + t * 512;
            if (idx < CC * 10) breg[t] = src[idx];
        }
    };
    auto write_stage = [&](int buf, int kc) {
        short4v vh, vl;
#pragma unroll
        for (int j = 0; j < 4; ++j) {
            int k = kc * 32 + kr0 + j;
            int ic = k / 9;
            int kk = k - ic * 9;
            float4 w4 = *(const float4*)&tw[kk][px][0];
            float v =      w4.x * g4[j][0];
            v = fmaf(w4.y, g4[j][1], v);
            v = fmaf(w4.z, g4[j][2], v);
            v = fmaf(w4.w, g4[j][3], v);
            unsigned short h = f2bf(v);
            vh[j] = (short)h;
            vl[j] = (short)f2bf(v - bf2f(h));
        }
        *(short4v*)&Al[buf][0][px][kr0] = vh;
        *(short4v*)&Al[buf][1][px][kr0] = vl;
        float4* dst = (float4*)&Bl[buf][0][0][0];
#pragma unroll
        for (int t = 0; t < NITER; ++t) {
            int idx = tid + t * 512;
            if (idx < CC * 10) dst[idx] = breg[t];
        }
    };

    __syncthreads();            // tw/ti visible
    load_stage(0);
    write_stage(0, 0);
    __syncthreads();

    for (int kc = 0; kc < 36; ++kc) {
        const int cur = kc & 1;
        if (kc < 35) load_stage(kc + 1);

        short8v af[2][2], bfr[2][2];
#pragma unroll
        for (int mi = 0; mi < 2; ++mi) {
            af[0][mi] = *(const short8v*)&Al[cur][0][m0 + mi * 16 + lrow][lkg];
            af[1][mi] = *(const short8v*)&Al[cur][1][m0 + mi * 16 + lrow][lkg];
        }
#pragma unroll
        for (int nj = 0; nj < 2; ++nj) {
            bfr[0][nj] = *(const short8v*)&Bl[cur][0][n0 + nj * 16 + lrow][lkg];
            bfr[1][nj] = *(const short8v*)&Bl[cur][1][n0 + nj * 16 + lrow][lkg];
        }
#pragma unroll
        for (int mi = 0; mi < 2; ++mi)
#pragma unroll
            for (int nj = 0; nj < 2; ++nj) {
                acc[mi][nj] = __builtin_amdgcn_mfma_f32_16x16x32_bf16(af[0][mi], bfr[0][nj], acc[mi][nj], 0, 0, 0);
                acc[mi][nj] = __builtin_amdgcn_mfma_f32_16x16x32_bf16(af[0][mi], bfr[1][nj], acc[mi][nj], 0, 0, 0);
                acc[mi][nj] = __builtin_amdgcn_mfma_f32_16x16x32_bf16(af[1][mi], bfr[0][nj], acc[mi][nj], 0, 0, 0);
            }

        if (kc < 35) write_stage(cur ^ 1, kc + 1);
        __syncthreads();
    }

#pragma unroll
    for (int nj = 0; nj < 2; ++nj) {
        int oc = n0 + nj * 16 + lrow;
        float bv = bd[oc];
#pragma unroll
        for (int mi = 0; mi < 2; ++mi) {
            floatx4 r = acc[mi][nj];
            int pxq = m0 + mi * 16 + (lane >> 4) * 4;
            *(float4*)(dout + ((size_t)b * CC + oc) * HWSZ + y * WW + pxq) =
                make_float4(r.x + bv, r.y + bv, r.z + bv, r.w + bv);
        }
    }
}

// mean/var -> (scale, shift) per channel
__global__ void bnstat_k(const float* __restrict__ ssum, const float* __restrict__ ssq,
                         const float* __restrict__ g, const float* __restrict__ bet,
                         float* __restrict__ scale, float* __restrict__ shift)
{
    int c = threadIdx.x;
    const float invn = 1.f / (4.f * HWSZ);
    float mean = ssum[c] * invn;
    float var  = ssq[c] * invn - mean * mean;
    float sc = g[c] * rsqrtf(var + 1e-5f);
    scale[c] = sc;
    shift[c] = fmaf(-mean, sc, bet[c]);
}

// out = relu(dout + bn2(y2)), vectorized float4 (all NCHW)
__global__ __launch_bounds__(256)
void final_k(const float* __restrict__ dout, const float* __restrict__ y2,
             const float* __restrict__ scale, const float* __restrict__ shift,
             float* __restrict__ out)
{
    int i = blockIdx.x * 256 + threadIdx.x;
    int c = (i >> 10) & 127;
    float4 d = reinterpret_cast<const float4*>(dout)[i];
    float4 yv = reinterpret_cast<const float4*>(y2)[i];
    float sc = scale[c], sh = shift[c];
    float4 r;
    r.x = fmaxf(d.x + fmaf(yv.x, sc, sh), 0.f);
    r.y = fmaxf(d.y + fmaf(yv.y, sc, sh), 0.f);
    r.z = fmaxf(d.z + fmaf(yv.z, sc, sh), 0.f);
    r.w = fmaxf(d.w + fmaf(yv.w, sc, sh), 0.f);
    reinterpret_cast<float4*>(out)[i] = r;
}

extern "C" void kernel_launch(void* const* d_in, const int* in_sizes, int n_in,
                              void* d_out, int out_size, void* d_ws, size_t ws_size,
                              hipStream_t stream)
{
    const float* x     = (const float*)d_in[0];
    const float* w_off = (const float*)d_in[1];
    const float* b_off = (const float*)d_in[2];
    const float* w_d   = (const float*)d_in[3];
    const float* b_d   = (const float*)d_in[4];
    const float* w1    = (const float*)d_in[5];
    const float* b1    = (const float*)d_in[6];
    const float* g1    = (const float*)d_in[7];
    const float* be1   = (const float*)d_in[8];
    const float* w2    = (const float*)d_in[9];
    const float* b2    = (const float*)d_in[10];
    const float* g2    = (const float*)d_in[11];
    const float* be2   = (const float*)d_in[12];

    float* ws      = (float*)d_ws;
    float* off_buf = ws;                       // 294912
    float* y1      = off_buf + 294912;         // 2097152
    float* y2      = y1 + 2097152;
    float* dob     = y2 + 2097152;
    float* wo_blob = dob + 2097152;            // 46080 f
    float* w1_blob = wo_blob + 46080;          // 184320 f
    float* w2_blob = w1_blob + 184320;
    float* wd_blob = w2_blob + 184320;
    float* st      = wd_blob + 184320;         // 1024 floats
    // st: sum1[128] sq1[128] sum2[128] sq2[128] scale1[128] shift1[128] scale2[128] shift2[128]

    hipMemsetAsync(st, 0, 512 * sizeof(float), stream);

    prepack_k<<<(36 * 32 * 32 + 255) / 256, 256, 0, stream>>>(w_off, (unsigned short*)wo_blob, 18, 32);
    prepack_k<<<(36 * 128 * 32 + 255) / 256, 256, 0, stream>>>(w1, (unsigned short*)w1_blob, 128, 128);
    prepack_k<<<(36 * 128 * 32 + 255) / 256, 256, 0, stream>>>(w2, (unsigned short*)w2_blob, 128, 128);
    prepack_k<<<(36 * 128 * 32 + 255) / 256, 256, 0, stream>>>(w_d, (unsigned short*)wd_blob, 128, 128);

    // offset conv: N=32 (18 used), 4 waves all on M
    gemm_k<0, 32, 256, 4, 1, 2, false, false><<<256, 256, 0, stream>>>(
        x, wo_blob, b_off, nullptr, nullptr, off_buf, nullptr, nullptr, 18);

    // deformable conv as sampled implicit GEMM -> dob
    dgemm_k<<<256, 512, 0, stream>>>(x, off_buf, wd_blob, b_d, dob);

    // conv1 + BN1 stats -> y1  (8 waves, pipelined)
    gemm_k<1, 128, 512, 2, 2, 2, false, true><<<256, 512, 0, stream>>>(
        x, w1_blob, b1, nullptr, nullptr, y1, st, st + 128, 128);
    bnstat_k<<<1, 128, 0, stream>>>(st, st + 128, g1, be1, st + 512, st + 640);

    // conv2 on relu(bn1(y1)) fused into A-staging + BN2 stats -> y2
    gemm_k<2, 128, 512, 2, 2, 2, true, true><<<256, 512, 0, stream>>>(
        y1, w2_blob, b2, st + 512, st + 640, y2, st + 256, st + 384, 128);
    bnstat_k<<<1, 128, 0, stream>>>(st + 256, st + 384, g2, be2, st + 768, st + 896);

    // out = relu(dob + bn2(y2))
    final_k<<<dim3(2048), 256, 0, stream>>>(dob, y2, st + 768, st + 896, (float*)d_out);
}